// Round 3
// baseline (366.805 us; speedup 1.0000x reference)
//
#include <hip/hip_runtime.h>

#define NEG -10000000.0f
#define QSCALE 0.18033688011112042f   // 0.125 (d^-0.5) * log2(e): softmax in exp2 domain

typedef __attribute__((ext_vector_type(8))) short bf16x8;
typedef __attribute__((ext_vector_type(4))) float f32x4;

static __device__ __forceinline__ short f2bf(float f) {
    unsigned int u = __float_as_uint(f);
    unsigned int r = (u + 0x7fffu + ((u >> 16) & 1u)) >> 16;
    return (short)r;
}

// pack two fp32 -> packed bf16x2 (round-half-up; exp outputs, ties measure-zero)
static __device__ __forceinline__ unsigned pack_bf16_2(float a, float b) {
    unsigned ua = __float_as_uint(a) + 0x8000u;
    unsigned ub = __float_as_uint(b) + 0x8000u;
    return __builtin_amdgcn_perm(ub, ua, 0x07060302u);
}

// async global->LDS, 16B per lane. lds base wave-uniform; lane i lands at +16*i.
static __device__ __forceinline__ void async_cp16(const void* g, void* l) {
    __builtin_amdgcn_global_load_lds(
        (const __attribute__((address_space(1))) unsigned int*)g,
        (__attribute__((address_space(3))) unsigned int*)l, 16, 0, 0);
}

// ---------------------------------------------------------------------------
__global__ void cvt_bf16(const float* __restrict__ src, short* __restrict__ dst, int n4) {
    int i = blockIdx.x * blockDim.x + threadIdx.x;
    if (i < n4) {
        float4 v = reinterpret_cast<const float4*>(src)[i];
        short4 o;
        o.x = f2bf(v.x); o.y = f2bf(v.y); o.z = f2bf(v.z); o.w = f2bf(v.w);
        reinterpret_cast<short4*>(dst)[i] = o;
    }
}

// ---------------------------------------------------------------------------
__global__ void transpose_cvt(const float* __restrict__ src, short* __restrict__ dst,
                              int rows, int cols) {
    __shared__ float tile[32][33];
    int bx = blockIdx.x * 32;
    int by = blockIdx.y * 32;
    int tx = threadIdx.x & 31, ty = threadIdx.x >> 5;
    for (int j = 0; j < 4; ++j)
        tile[ty + j * 8][tx] = src[(size_t)(by + ty + j * 8) * cols + bx + tx];
    __syncthreads();
    for (int j = 0; j < 4; ++j)
        dst[(size_t)(bx + ty + j * 8) * rows + by + tx] = f2bf(tile[tx][ty + j * 8]);
}

// ---------------------------------------------------------------------------
__global__ void mask_flags(const int* __restrict__ attn_mask, int* __restrict__ flags) {
    int blk = blockIdx.x;
    int qt = blk >> 5, kt = blk & 31;
    int tid = threadIdx.x;
    __shared__ int blockok;
    if (tid == 0) blockok = 1;
    __syncthreads();
    int ok = 1;
    for (int j = 0; j < 32; ++j) {
        int idx = j * 256 + tid;
        int qr = qt * 128 + (idx >> 6);
        int kc = kt * 64 + (idx & 63);
        ok &= (attn_mask[(size_t)qr * 2048 + kc] != 0);
    }
    if (!ok) blockok = 0;
    __syncthreads();
    if (tid == 0) flags[blk] = blockok;
}

__global__ void pad_flags(const int* __restrict__ padding, int* __restrict__ pf) {
    int t = threadIdx.x;           // 128 threads
    int b = t >> 5, kt = t & 31;
    int any = 0;
    for (int j = 0; j < 64; ++j) any |= (padding[b * 2048 + kt * 64 + j] > 0);
    pf[t] = any;
}

// ---------------------------------------------------------------------------
// bf16 GEMM (unchanged from R2): 128x128x64 tile, global_load_lds staging,
// XOR-swizzled LDS chunks. mode 0: QKV scatter epilogue; mode 1: proj + bias.
// ---------------------------------------------------------------------------
__global__ __launch_bounds__(256, 2) void gemm_bf16(
    const short* __restrict__ A, const short* __restrict__ Bt, int mode,
    short* __restrict__ q_ws, short* __restrict__ k_ws, short* __restrict__ v_ws,
    float* __restrict__ out, const float* __restrict__ bias) {
    const int K = 1024;
    __shared__ short As[128][64];
    __shared__ short Bs[128][64];
    int tid = threadIdx.x, lane = tid & 63, w = tid >> 6;
    int wm = w & 1, wn = w >> 1;
    int m0 = blockIdx.y * 128, n0 = blockIdx.x * 128;
    int col = lane & 15, quad = lane >> 4;
    int l8 = lane >> 3, j8 = lane & 7;

    f32x4 acc[4][4] = {};

    for (int k0 = 0; k0 < K; k0 += 64) {
        for (int c = 0; c < 4; ++c) {
            int rr = w * 32 + c * 8 + l8;
            int sw = (j8 ^ (rr & 7)) << 3;
            async_cp16(&A[(size_t)(m0 + rr) * K + k0 + sw], &As[w * 32 + c * 8][0]);
            async_cp16(&Bt[(size_t)(n0 + rr) * K + k0 + sw], &Bs[w * 32 + c * 8][0]);
        }
        __syncthreads();
        for (int ks = 0; ks < 2; ++ks) {
            bf16x8 af[4], bfr[4];
            for (int mt = 0; mt < 4; ++mt)
                af[mt] = *reinterpret_cast<const bf16x8*>(
                    &As[wm * 64 + mt * 16 + col][((ks * 4 + quad) ^ (col & 7)) << 3]);
            for (int nt = 0; nt < 4; ++nt)
                bfr[nt] = *reinterpret_cast<const bf16x8*>(
                    &Bs[wn * 64 + nt * 16 + col][((ks * 4 + quad) ^ (col & 7)) << 3]);
            for (int mt = 0; mt < 4; ++mt)
                for (int nt = 0; nt < 4; ++nt)
                    acc[mt][nt] = __builtin_amdgcn_mfma_f32_16x16x32_bf16(af[mt], bfr[nt], acc[mt][nt], 0, 0, 0);
        }
        __syncthreads();
    }

    if (mode == 0) {
        int which = n0 >> 10;
        int cb = n0 & 1023;
        if (which == 2) {
            for (int mt = 0; mt < 4; ++mt) {
                int m = m0 + wm * 64 + mt * 16 + quad * 4;
                int b = m >> 11, n = m & 2047;
                for (int nt = 0; nt < 4; ++nt) {
                    int c = cb + wn * 64 + nt * 16 + col;
                    int h = c >> 6, dd = c & 63;
                    short4 pk;
                    for (int r = 0; r < 4; ++r) ((short*)&pk)[r] = f2bf(acc[mt][nt][r]);
                    *reinterpret_cast<short4*>(&v_ws[((size_t)((b * 16 + h) * 64 + dd)) * 2048 + n]) = pk;
                }
            }
        } else {
            short* dst = (which == 0) ? q_ws : k_ws;
            float scl = (which == 0) ? QSCALE : 1.0f;
            for (int mt = 0; mt < 4; ++mt)
                for (int nt = 0; nt < 4; ++nt)
                    for (int r = 0; r < 4; ++r) {
                        int m = m0 + wm * 64 + mt * 16 + quad * 4 + r;
                        int c = cb + wn * 64 + nt * 16 + col;
                        int b = m >> 11, n = m & 2047;
                        int h = c >> 6, dd = c & 63;
                        dst[((size_t)(b * 16 + h) * 2048 + n) * 64 + dd] = f2bf(acc[mt][nt][r] * scl);
                    }
        }
    } else {
        for (int mt = 0; mt < 4; ++mt)
            for (int nt = 0; nt < 4; ++nt)
                for (int r = 0; r < 4; ++r) {
                    int m = m0 + wm * 64 + mt * 16 + quad * 4 + r;
                    int c = n0 + wn * 64 + nt * 16 + col;
                    out[(size_t)m * 1024 + c] = acc[mt][nt][r] + bias[c];
                }
    }
}

// ---------------------------------------------------------------------------
// Flash attention v3. Grid (16 q-tiles, 64 b*h). Q-tile 128, K-tile 64, d=64.
// - K tile double-buffered in LDS -> ONE barrier/iter, staging latency hidden
//   (prefetch issued a full compute phase before the barrier that drains it).
// - V frags loaded direct from global (16B contiguous in v_ws[bh][dd][n]),
//   L1/L2-served: V staging + V LDS reads eliminated.
// - P roundtrip through wave-private QP rows (no barrier needed for it).
// LDS = 16K (QP) + 16K (Ks dbuf) + 512 = 33.2 KB -> 4 blocks/CU (grid packs 4/CU).
// ---------------------------------------------------------------------------
__global__ __launch_bounds__(256, 4) void flash_attn(
    const short* __restrict__ q_ws, const short* __restrict__ k_ws,
    const short* __restrict__ v_ws, const int* __restrict__ aflags,
    const int* __restrict__ pflags, const int* __restrict__ padding,
    const int* __restrict__ attn_mask, short* __restrict__ xb) {
    const int Nn = 2048, D = 64;
    __shared__ short QP[128][64];      // Q frags source, then P roundtrip (wave-private)
    __shared__ short Ks[2][64][64];    // double-buffered K tile
    __shared__ __align__(16) float padb[2][64];

    int tid = threadIdx.x, lane = tid & 63, w = tid >> 6;
    int col = lane & 15, quad = lane >> 4;
    int bh = blockIdx.y, b = bh >> 4, h = bh & 15;
    int q0 = blockIdx.x * 128, qt = blockIdx.x;
    int l8 = lane >> 3, j8 = lane & 7;
    int swz = (j8 ^ l8) << 3;          // lane-const gather swizzle (row&7 == l8)

    // stage Q once (rows w*32 + c*8 + l8)
    {
        const short* qg = q_ws + ((size_t)bh * Nn + q0 + w * 32 + l8) * D + swz;
        async_cp16(qg,          &QP[w * 32][0]);
        async_cp16(qg + 8 * D,  &QP[w * 32 + 8][0]);
        async_cp16(qg + 16 * D, &QP[w * 32 + 16][0]);
        async_cp16(qg + 24 * D, &QP[w * 32 + 24][0]);
    }
    // stage K tile 0 into buffer 0
    const short* kg = k_ws + ((size_t)bh * Nn + w * 16 + l8) * D + swz;
    async_cp16(kg,         &Ks[0][w * 16][0]);
    async_cp16(kg + 8 * D, &Ks[0][w * 16 + 8][0]);
    if (pflags[b * 32] && tid < 64)
        padb[0][tid] = (padding[b * Nn + tid] > 0) ? NEG : 0.f;
    __syncthreads();   // drains Q + K0 staging

    // persistent Q B-frags; QP rows w*32..+31 wave-private afterwards
    bf16x8 qf[2][2];
    for (int t = 0; t < 2; ++t)
        for (int ks = 0; ks < 2; ++ks)
            qf[t][ks] = *reinterpret_cast<const bf16x8*>(
                &QP[w * 32 + t * 16 + col][((ks * 4 + quad) ^ (col & 7)) << 3]);

    f32x4 oacc[2][4] = {};
    f32x4 lacc[2] = {};

    for (int kt = 0; kt < 32; ++kt) {
        int cur = kt & 1;
        int k0 = kt * 64;

        // prefetch next K tile into the other buffer (drained by end barrier,
        // a full compute phase later -> latency hidden)
        if (kt < 31) {
            const short* kn = kg + (size_t)(kt + 1) * 64 * D;
            async_cp16(kn,         &Ks[cur ^ 1][w * 16][0]);
            async_cp16(kn + 8 * D, &Ks[cur ^ 1][w * 16 + 8][0]);
            if (pflags[b * 32 + kt + 1] && tid < 64)
                padb[cur ^ 1][tid] = (padding[b * Nn + k0 + 64 + tid] > 0) ? NEG : 0.f;
        }

        // S^T = K * Q^T  (kcol x qrow), 16 MFMA from 8 kf loads (qf persistent)
        f32x4 sacc[4][2] = {};
        for (int ks = 0; ks < 2; ++ks)
            for (int mt = 0; mt < 4; ++mt) {
                bf16x8 kf = *reinterpret_cast<const bf16x8*>(
                    &Ks[cur][mt * 16 + col][((ks * 4 + quad) ^ (col & 7)) << 3]);
                sacc[mt][0] = __builtin_amdgcn_mfma_f32_16x16x32_bf16(kf, qf[0][ks], sacc[mt][0], 0, 0, 0);
                sacc[mt][1] = __builtin_amdgcn_mfma_f32_16x16x32_bf16(kf, qf[1][ks], sacc[mt][1], 0, 0, 0);
            }

        // V frags ks=0 direct from global; exp phase below hides the latency
        const short* vg = v_ws + ((size_t)bh * D + col) * Nn + k0 + quad * 8;
        bf16x8 vf0[4], vf1[4];
        for (int nt = 0; nt < 4; ++nt)
            vf0[nt] = *reinterpret_cast<const bf16x8*>(vg + (size_t)nt * 16 * Nn);

        // slow paths (never taken for this input; kept for correctness)
        if (!aflags[qt * 32 + kt]) {
            for (int mt = 0; mt < 4; ++mt)
                for (int t = 0; t < 2; ++t)
                    for (int r = 0; r < 4; ++r) {
                        int kc = k0 + mt * 16 + quad * 4 + r;
                        int qr = q0 + w * 32 + t * 16 + col;
                        if (attn_mask[(size_t)qr * Nn + kc] == 0) sacc[mt][t][r] = NEG;
                    }
        }
        if (pflags[b * 32 + kt]) {
            for (int mt = 0; mt < 4; ++mt) {
                f32x4 pb = *reinterpret_cast<const f32x4*>(&padb[cur][mt * 16 + quad * 4]);
                for (int t = 0; t < 2; ++t)
                    for (int r = 0; r < 4; ++r) sacc[mt][t][r] += pb[r];
            }
        }

        // P = exp2(S) (fixed-max softmax: scores bounded), pack -> wave-private rows
        for (int t = 0; t < 2; ++t) {
            int qrow = w * 32 + t * 16 + col;
            for (int mt = 0; mt < 4; ++mt) {
                f32x4 e;
                e[0] = __builtin_amdgcn_exp2f(sacc[mt][t][0]);
                e[1] = __builtin_amdgcn_exp2f(sacc[mt][t][1]);
                e[2] = __builtin_amdgcn_exp2f(sacc[mt][t][2]);
                e[3] = __builtin_amdgcn_exp2f(sacc[mt][t][3]);
                lacc[t] += e;
                unsigned p0 = pack_bf16_2(e[0], e[1]);
                unsigned p1 = pack_bf16_2(e[2], e[3]);
                int chunk = (mt * 2 + (quad >> 1)) ^ (col & 7);
                *reinterpret_cast<uint2*>(&QP[qrow][(chunk << 3) + ((quad & 1) << 2)]) =
                    make_uint2(p0, p1);
            }
        }

        // V frags ks=1 (short gap to use; mostly L1 hits)
        for (int nt = 0; nt < 4; ++nt)
            vf1[nt] = *reinterpret_cast<const bf16x8*>(vg + (size_t)nt * 16 * Nn + 32);

        // O += P @ V  (P roundtrip wave-local: compiler lgkmcnt suffices)
        for (int t = 0; t < 2; ++t) {
            bf16x8 pf = *reinterpret_cast<const bf16x8*>(
                &QP[w * 32 + t * 16 + col][(quad ^ (col & 7)) << 3]);
            for (int nt = 0; nt < 4; ++nt)
                oacc[t][nt] = __builtin_amdgcn_mfma_f32_16x16x32_bf16(pf, vf0[nt], oacc[t][nt], 0, 0, 0);
        }
        for (int t = 0; t < 2; ++t) {
            bf16x8 pf = *reinterpret_cast<const bf16x8*>(
                &QP[w * 32 + t * 16 + col][((4 + quad) ^ (col & 7)) << 3]);
            for (int nt = 0; nt < 4; ++nt)
                oacc[t][nt] = __builtin_amdgcn_mfma_f32_16x16x32_bf16(pf, vf1[nt], oacc[t][nt], 0, 0, 0);
        }

        __syncthreads();   // all waves done with Ks[cur]; drains next-tile staging
    }

    // epilogue: O /= l, write bf16 x[b][n][h*64+dd]
    for (int t = 0; t < 2; ++t) {
        float ls = lacc[t][0] + lacc[t][1] + lacc[t][2] + lacc[t][3];
        ls += __shfl_xor(ls, 16);
        ls += __shfl_xor(ls, 32);
        for (int r = 0; r < 4; ++r) {
            float lv = __shfl(ls, quad * 4 + r, 16);
            float inv = 1.f / lv;
            int n = q0 + w * 32 + t * 16 + quad * 4 + r;
            for (int nt = 0; nt < 4; ++nt) {
                int dd = nt * 16 + col;
                xb[((size_t)(b * Nn + n)) * 1024 + h * 64 + dd] = f2bf(oacc[t][nt][r] * inv);
            }
        }
    }
}

// ---------------------------------------------------------------------------
extern "C" void kernel_launch(void* const* d_in, const int* in_sizes, int n_in,
                              void* d_out, int out_size, void* d_ws, size_t ws_size,
                              hipStream_t stream) {
    const float* x        = (const float*)d_in[0];   // (4,2048,1024) fp32
    const int* attn_mask  = (const int*)d_in[1];     // (2048,2048)
    const int* padding    = (const int*)d_in[2];     // (4,2048)
    const float* W_qkv    = (const float*)d_in[3];   // (1024,3072)
    const float* W_proj   = (const float*)d_in[4];   // (1024,1024)
    const float* b_proj   = (const float*)d_in[5];   // (1024,)
    float* out            = (float*)d_out;

    char* ws = (char*)d_ws;
    short* Xb   = (short*)(ws);                 // 16 MB  (8192x1024 bf16)
    short* Wqt  = (short*)(ws + (16u << 20));   // 6 MB   (3072x1024 bf16, W_qkv^T)
    short* Wpt  = (short*)(ws + (22u << 20));   // 2 MB   (1024x1024 bf16, W_proj^T)
    short* q_ws = (short*)(ws + (24u << 20));   // 16 MB  (64,2048,64) pre-scaled (exp2 dom.)
    short* k_ws = (short*)(ws + (40u << 20));   // 16 MB  (64,2048,64)
    short* v_ws = (short*)(ws + (56u << 20));   // 16 MB  (64,64,2048) transposed
    short* xbuf = (short*)(ws + (72u << 20));   // 16 MB  (8192x1024 bf16) attn out
    int*  flags = (int*)(ws + (88u << 20));     // attn flags [512] + pad flags [128]

    cvt_bf16<<<8192, 256, 0, stream>>>(x, Xb, 8388608 / 4);
    transpose_cvt<<<dim3(3072 / 32, 1024 / 32), 256, 0, stream>>>(W_qkv, Wqt, 1024, 3072);
    transpose_cvt<<<dim3(1024 / 32, 1024 / 32), 256, 0, stream>>>(W_proj, Wpt, 1024, 1024);
    mask_flags<<<512, 256, 0, stream>>>(attn_mask, flags);
    pad_flags<<<1, 128, 0, stream>>>(padding, flags + 512);

    gemm_bf16<<<dim3(3072 / 128, 8192 / 128), 256, 0, stream>>>(
        Xb, Wqt, 0, q_ws, k_ws, v_ws, nullptr, nullptr);

    flash_attn<<<dim3(16, 64), 256, 0, stream>>>(
        q_ws, k_ws, v_ws, flags, flags + 512, padding, attn_mask, xbuf);

    gemm_bf16<<<dim3(1024 / 128, 8192 / 128), 256, 0, stream>>>(
        xbuf, Wpt, 1, nullptr, nullptr, nullptr, out, b_proj);
}

// Round 4
// 287.227 us; speedup vs baseline: 1.2771x; 1.2771x over previous
//
#include <hip/hip_runtime.h>

#define NEG -10000000.0f
#define QSCALE 0.18033688011112042f   // 0.125 (d^-0.5) * log2(e): softmax in exp2 domain

typedef __attribute__((ext_vector_type(8))) short bf16x8;
typedef __attribute__((ext_vector_type(4))) float f32x4;

static __device__ __forceinline__ short f2bf(float f) {
    unsigned int u = __float_as_uint(f);
    unsigned int r = (u + 0x7fffu + ((u >> 16) & 1u)) >> 16;
    return (short)r;
}

// pack two fp32 -> packed bf16x2 (round-half-up; exp outputs, ties measure-zero)
static __device__ __forceinline__ unsigned pack_bf16_2(float a, float b) {
    unsigned ua = __float_as_uint(a) + 0x8000u;
    unsigned ub = __float_as_uint(b) + 0x8000u;
    return __builtin_amdgcn_perm(ub, ua, 0x07060302u);
}

// async global->LDS, 16B per lane. lds base wave-uniform; lane i lands at +16*i.
static __device__ __forceinline__ void async_cp16(const void* g, void* l) {
    __builtin_amdgcn_global_load_lds(
        (const __attribute__((address_space(1))) unsigned int*)g,
        (__attribute__((address_space(3))) unsigned int*)l, 16, 0, 0);
}

// ---------------------------------------------------------------------------
__global__ void cvt_bf16(const float* __restrict__ src, short* __restrict__ dst, int n4) {
    int i = blockIdx.x * blockDim.x + threadIdx.x;
    if (i < n4) {
        float4 v = reinterpret_cast<const float4*>(src)[i];
        short4 o;
        o.x = f2bf(v.x); o.y = f2bf(v.y); o.z = f2bf(v.z); o.w = f2bf(v.w);
        reinterpret_cast<short4*>(dst)[i] = o;
    }
}

// ---------------------------------------------------------------------------
__global__ void transpose_cvt(const float* __restrict__ src, short* __restrict__ dst,
                              int rows, int cols) {
    __shared__ float tile[32][33];
    int bx = blockIdx.x * 32;
    int by = blockIdx.y * 32;
    int tx = threadIdx.x & 31, ty = threadIdx.x >> 5;
    for (int j = 0; j < 4; ++j)
        tile[ty + j * 8][tx] = src[(size_t)(by + ty + j * 8) * cols + bx + tx];
    __syncthreads();
    for (int j = 0; j < 4; ++j)
        dst[(size_t)(bx + ty + j * 8) * rows + by + tx] = f2bf(tile[tx][ty + j * 8]);
}

// ---------------------------------------------------------------------------
__global__ void mask_flags(const int* __restrict__ attn_mask, int* __restrict__ flags) {
    int blk = blockIdx.x;
    int qt = blk >> 5, kt = blk & 31;
    int tid = threadIdx.x;
    __shared__ int blockok;
    if (tid == 0) blockok = 1;
    __syncthreads();
    int ok = 1;
    for (int j = 0; j < 32; ++j) {
        int idx = j * 256 + tid;
        int qr = qt * 128 + (idx >> 6);
        int kc = kt * 64 + (idx & 63);
        ok &= (attn_mask[(size_t)qr * 2048 + kc] != 0);
    }
    if (!ok) blockok = 0;
    __syncthreads();
    if (tid == 0) flags[blk] = blockok;
}

__global__ void pad_flags(const int* __restrict__ padding, int* __restrict__ pf) {
    int t = threadIdx.x;           // 128 threads
    int b = t >> 5, kt = t & 31;
    int any = 0;
    for (int j = 0; j < 64; ++j) any |= (padding[b * 2048 + kt * 64 + j] > 0);
    pf[t] = any;
}

// ---------------------------------------------------------------------------
// bf16 GEMM: 128x128x64 tile, global_load_lds staging, XOR-swizzled LDS chunks.
// R4: epilogues round-trip C through LDS (reusing staging smem) so ALL global
// stores are coalesced int4/float4 (was: 2B/4B scatter storms).
// mode 0: QKV -> q (QSCALE-folded), k, v (transposed); mode 1: proj + bias.
// ---------------------------------------------------------------------------
__global__ __launch_bounds__(256, 2) void gemm_bf16(
    const short* __restrict__ A, const short* __restrict__ Bt, int mode,
    short* __restrict__ q_ws, short* __restrict__ k_ws, short* __restrict__ v_ws,
    float* __restrict__ out, const float* __restrict__ bias) {
    const int K = 1024;
    __shared__ __align__(16) short smem[2][128][64];   // As/Bs, reused by epilogue
    short (*As)[64] = smem[0];
    short (*Bs)[64] = smem[1];
    int tid = threadIdx.x, lane = tid & 63, w = tid >> 6;
    int wm = w & 1, wn = w >> 1;
    int m0 = blockIdx.y * 128, n0 = blockIdx.x * 128;
    int col = lane & 15, quad = lane >> 4;
    int l8 = lane >> 3, j8 = lane & 7;

    f32x4 acc[4][4] = {};

    for (int k0 = 0; k0 < K; k0 += 64) {
        for (int c = 0; c < 4; ++c) {
            int rr = w * 32 + c * 8 + l8;
            int sw = (j8 ^ (rr & 7)) << 3;
            async_cp16(&A[(size_t)(m0 + rr) * K + k0 + sw], &As[w * 32 + c * 8][0]);
            async_cp16(&Bt[(size_t)(n0 + rr) * K + k0 + sw], &Bs[w * 32 + c * 8][0]);
        }
        __syncthreads();
        for (int ks = 0; ks < 2; ++ks) {
            bf16x8 af[4], bfr[4];
            for (int mt = 0; mt < 4; ++mt)
                af[mt] = *reinterpret_cast<const bf16x8*>(
                    &As[wm * 64 + mt * 16 + col][((ks * 4 + quad) ^ (col & 7)) << 3]);
            for (int nt = 0; nt < 4; ++nt)
                bfr[nt] = *reinterpret_cast<const bf16x8*>(
                    &Bs[wn * 64 + nt * 16 + col][((ks * 4 + quad) ^ (col & 7)) << 3]);
            for (int mt = 0; mt < 4; ++mt)
                for (int nt = 0; nt < 4; ++nt)
                    acc[mt][nt] = __builtin_amdgcn_mfma_f32_16x16x32_bf16(af[mt], bfr[nt], acc[mt][nt], 0, 0, 0);
        }
        __syncthreads();   // also frees smem for the epilogue after last iter
    }

    short* L = &smem[0][0][0];   // 128x128 bf16 view (32 KB)

    if (mode == 0) {
        int which = n0 >> 10;    // block-uniform: 0=Q 1=K 2=V
        int cb = n0 & 1023;
        int b = m0 >> 11, nb = m0 & 2047, hb = cb >> 6;
        if (which == 2) {
            // V wants [bh][dd][n]: stage transposed Lt[c][m], m-chunks rotated by c
            for (int mt = 0; mt < 4; ++mt)
                for (int nt = 0; nt < 4; ++nt) {
                    int ml = wm * 64 + mt * 16 + quad * 4;
                    int cl = wn * 64 + nt * 16 + col;
                    int mp = (ml + 8 * cl) & 127;
                    short4 pk;
                    for (int r = 0; r < 4; ++r) ((short*)&pk)[r] = f2bf(acc[mt][nt][r]);
                    *reinterpret_cast<short4*>(&L[cl * 128 + mp]) = pk;
                }
            __syncthreads();
            for (int it = 0; it < 8; ++it) {
                int chunk = it * 256 + tid;            // 128 c-rows x 16 chunks
                int c = chunk >> 4, j = chunk & 15;
                int h = hb + (c >> 6), dd = c & 63;
                int4 val = *reinterpret_cast<const int4*>(&L[c * 128 + (((j + c) & 15) << 3)]);
                *reinterpret_cast<int4*>(
                    &v_ws[((size_t)((b * 16 + h) * 64 + dd)) * 2048 + nb + j * 8]) = val;
            }
        } else {
            short* dst = (which == 0) ? q_ws : k_ws;
            float scl = (which == 0) ? QSCALE : 1.0f;
            // L[m][c], c-chunks rotated by m (reads 2-way/free)
            for (int mt = 0; mt < 4; ++mt)
                for (int nt = 0; nt < 4; ++nt)
                    for (int r = 0; r < 4; ++r) {
                        int ml = wm * 64 + mt * 16 + quad * 4 + r;
                        int cl = wn * 64 + nt * 16 + col;
                        L[ml * 128 + ((cl + 8 * ml) & 127)] = f2bf(acc[mt][nt][r] * scl);
                    }
            __syncthreads();
            for (int it = 0; it < 8; ++it) {
                int chunk = it * 256 + tid;            // 128 rows x 16 chunks
                int row = chunk >> 4, j = chunk & 15;
                int h = hb + (j >> 3), dd = (j & 7) * 8;
                int4 val = *reinterpret_cast<const int4*>(&L[row * 128 + (((j + row) & 15) << 3)]);
                *reinterpret_cast<int4*>(
                    &dst[((size_t)(b * 16 + h) * 2048 + nb + row) * 64 + dd]) = val;
            }
        }
    } else {
        // proj: fp32 out + bias, via LDS in two 64-row halves (32 KB each)
        float* Lf = reinterpret_cast<float*>(L);       // 64 x 128 fp32
        for (int half = 0; half < 2; ++half) {
            if (wm == half) {
                for (int mt = 0; mt < 4; ++mt)
                    for (int nt = 0; nt < 4; ++nt)
                        for (int r = 0; r < 4; ++r) {
                            int ml = mt * 16 + quad * 4 + r;       // 0..63 in half
                            int cl = wn * 64 + nt * 16 + col;
                            Lf[ml * 128 + cl] = acc[mt][nt][r];
                        }
            }
            __syncthreads();
            for (int it = 0; it < 8; ++it) {
                int chunk = it * 256 + tid;            // 64 rows x 32 chunks
                int row = chunk >> 5, j = chunk & 31;
                float4 val = *reinterpret_cast<const float4*>(&Lf[row * 128 + j * 4]);
                float4 bv = *reinterpret_cast<const float4*>(&bias[n0 + j * 4]);
                val.x += bv.x; val.y += bv.y; val.z += bv.z; val.w += bv.w;
                *reinterpret_cast<float4*>(
                    &out[(size_t)(m0 + half * 64 + row) * 1024 + n0 + j * 4]) = val;
            }
            __syncthreads();   // half1 writers must wait for half0 readers
        }
    }
}

// ---------------------------------------------------------------------------
// Flash attention (R2-proven version, 96.5 us). Grid (16 q-tiles, 64 b*h).
// Q-tile 128, K-tile 64, d=64. S^T = K * Q^T in exp2 domain.
// LDS 32.2 KB (Pt aliases Q staging; XOR-swizzled chunks) -> 4 blocks/CU.
// ---------------------------------------------------------------------------
__global__ __launch_bounds__(256, 4) void flash_attn(
    const short* __restrict__ q_ws, const short* __restrict__ k_ws,
    const short* __restrict__ v_ws, const int* __restrict__ aflags,
    const int* __restrict__ pflags, const int* __restrict__ padding,
    const int* __restrict__ attn_mask, short* __restrict__ xb) {
    const int Nn = 2048, D = 64;
    __shared__ short QP[128][64];   // Q staging, then P tile (both wave-private rows)
    __shared__ short Ks[64][64];
    __shared__ short Vt[64][64];    // V^T: [d][kcol]
    __shared__ __align__(16) float padb[64];

    int tid = threadIdx.x, lane = tid & 63, w = tid >> 6;
    int col = lane & 15, quad = lane >> 4;
    int bh = blockIdx.y, b = bh >> 4, h = bh & 15;
    int q0 = blockIdx.x * 128, qt = blockIdx.x;
    int l8 = lane >> 3, j8 = lane & 7;

    // stage Q (swizzled gather -> linear lane-ordered LDS)
    for (int c = 0; c < 4; ++c) {
        int rr = w * 32 + c * 8 + l8;
        async_cp16(&q_ws[((size_t)bh * Nn + q0 + rr) * D + ((j8 ^ (rr & 7)) << 3)],
                   &QP[w * 32 + c * 8][0]);
    }
    __syncthreads();

    // persistent Q B-frags; QP rows w*32..+31 are wave-private from here on
    bf16x8 qf[2][2];
    for (int t = 0; t < 2; ++t)
        for (int ks = 0; ks < 2; ++ks)
            qf[t][ks] = *reinterpret_cast<const bf16x8*>(
                &QP[w * 32 + t * 16 + col][((ks * 4 + quad) ^ (col & 7)) << 3]);

    f32x4 oacc[2][4] = {};
    f32x4 lacc[2] = {};

    for (int kt = 0; kt < 32; ++kt) {
        int k0 = kt * 64;
        for (int c = 0; c < 2; ++c) {
            int rr = w * 16 + c * 8 + l8;
            int sw = (j8 ^ (rr & 7)) << 3;
            async_cp16(&k_ws[((size_t)bh * Nn + k0 + rr) * D + sw], &Ks[w * 16 + c * 8][0]);
            async_cp16(&v_ws[((size_t)bh * D + rr) * Nn + k0 + sw], &Vt[w * 16 + c * 8][0]);
        }
        int pflag = pflags[b * 32 + kt];
        if (pflag && tid < 64) padb[tid] = (padding[b * Nn + k0 + tid] > 0) ? NEG : 0.f;
        __syncthreads();

        // S^T (kcol x qrow): A = K tile (4 mt), B = Q^T (2 qrow tiles per wave)
        f32x4 sacc[4][2] = {};
        for (int ks = 0; ks < 2; ++ks) {
            bf16x8 kf[4];
            for (int mt = 0; mt < 4; ++mt)
                kf[mt] = *reinterpret_cast<const bf16x8*>(
                    &Ks[mt * 16 + col][((ks * 4 + quad) ^ (col & 7)) << 3]);
            for (int mt = 0; mt < 4; ++mt)
                for (int t = 0; t < 2; ++t)
                    sacc[mt][t] = __builtin_amdgcn_mfma_f32_16x16x32_bf16(kf[mt], qf[t][ks], sacc[mt][t], 0, 0, 0);
        }

        if (!aflags[qt * 32 + kt]) {   // slow path: per-element attn mask
            for (int mt = 0; mt < 4; ++mt)
                for (int t = 0; t < 2; ++t)
                    for (int r = 0; r < 4; ++r) {
                        int kc = k0 + mt * 16 + quad * 4 + r;
                        int qr = q0 + w * 32 + t * 16 + col;
                        if (attn_mask[(size_t)qr * Nn + kc] == 0) sacc[mt][t][r] = NEG;
                    }
        }
        if (pflag) {                   // slow path: padding bias per kcol
            for (int mt = 0; mt < 4; ++mt) {
                f32x4 pb = *reinterpret_cast<const f32x4*>(&padb[mt * 16 + quad * 4]);
                for (int t = 0; t < 2; ++t)
                    for (int r = 0; r < 4; ++r) sacc[mt][t][r] += pb[r];
            }
        }

        // P = exp2(S) (fixed-max softmax: scores bounded), pack -> wave-private rows
        for (int t = 0; t < 2; ++t) {
            int qrow = w * 32 + t * 16 + col;
            for (int mt = 0; mt < 4; ++mt) {
                f32x4 e;
                e[0] = __builtin_amdgcn_exp2f(sacc[mt][t][0]);
                e[1] = __builtin_amdgcn_exp2f(sacc[mt][t][1]);
                e[2] = __builtin_amdgcn_exp2f(sacc[mt][t][2]);
                e[3] = __builtin_amdgcn_exp2f(sacc[mt][t][3]);
                lacc[t] += e;
                unsigned p0 = pack_bf16_2(e[0], e[1]);
                unsigned p1 = pack_bf16_2(e[2], e[3]);
                int chunk = (mt * 2 + (quad >> 1)) ^ (col & 7);
                *reinterpret_cast<uint2*>(&QP[qrow][(chunk << 3) + ((quad & 1) << 2)]) =
                    make_uint2(p0, p1);
            }
        }

        // O += P @ V (P roundtrip wave-local: compiler lgkmcnt suffices, no barrier)
        for (int ks = 0; ks < 2; ++ks) {
            bf16x8 pf[2], vf[4];
            for (int t = 0; t < 2; ++t)
                pf[t] = *reinterpret_cast<const bf16x8*>(
                    &QP[w * 32 + t * 16 + col][((ks * 4 + quad) ^ (col & 7)) << 3]);
            for (int nt = 0; nt < 4; ++nt)
                vf[nt] = *reinterpret_cast<const bf16x8*>(
                    &Vt[nt * 16 + col][((ks * 4 + quad) ^ (col & 7)) << 3]);
            for (int t = 0; t < 2; ++t)
                for (int nt = 0; nt < 4; ++nt)
                    oacc[t][nt] = __builtin_amdgcn_mfma_f32_16x16x32_bf16(pf[t], vf[nt], oacc[t][nt], 0, 0, 0);
        }
        __syncthreads();   // protect Ks/Vt/padb before next staging
    }

    // epilogue: O /= l, write bf16 x[b][n][h*64+dd]
    for (int t = 0; t < 2; ++t) {
        float ls = lacc[t][0] + lacc[t][1] + lacc[t][2] + lacc[t][3];
        ls += __shfl_xor(ls, 16);
        ls += __shfl_xor(ls, 32);
        for (int r = 0; r < 4; ++r) {
            float lv = __shfl(ls, quad * 4 + r, 16);
            float inv = 1.f / lv;
            int n = q0 + w * 32 + t * 16 + quad * 4 + r;
            for (int nt = 0; nt < 4; ++nt) {
                int dd = nt * 16 + col;
                xb[((size_t)(b * Nn + n)) * 1024 + h * 64 + dd] = f2bf(oacc[t][nt][r] * inv);
            }
        }
    }
}

// ---------------------------------------------------------------------------
extern "C" void kernel_launch(void* const* d_in, const int* in_sizes, int n_in,
                              void* d_out, int out_size, void* d_ws, size_t ws_size,
                              hipStream_t stream) {
    const float* x        = (const float*)d_in[0];   // (4,2048,1024) fp32
    const int* attn_mask  = (const int*)d_in[1];     // (2048,2048)
    const int* padding    = (const int*)d_in[2];     // (4,2048)
    const float* W_qkv    = (const float*)d_in[3];   // (1024,3072)
    const float* W_proj   = (const float*)d_in[4];   // (1024,1024)
    const float* b_proj   = (const float*)d_in[5];   // (1024,)
    float* out            = (float*)d_out;

    char* ws = (char*)d_ws;
    short* Xb   = (short*)(ws);                 // 16 MB  (8192x1024 bf16)
    short* Wqt  = (short*)(ws + (16u << 20));   // 6 MB   (3072x1024 bf16, W_qkv^T)
    short* Wpt  = (short*)(ws + (22u << 20));   // 2 MB   (1024x1024 bf16, W_proj^T)
    short* q_ws = (short*)(ws + (24u << 20));   // 16 MB  (64,2048,64) pre-scaled (exp2 dom.)
    short* k_ws = (short*)(ws + (40u << 20));   // 16 MB  (64,2048,64)
    short* v_ws = (short*)(ws + (56u << 20));   // 16 MB  (64,64,2048) transposed
    short* xbuf = (short*)(ws + (72u << 20));   // 16 MB  (8192x1024 bf16) attn out
    int*  flags = (int*)(ws + (88u << 20));     // attn flags [512] + pad flags [128]

    cvt_bf16<<<8192, 256, 0, stream>>>(x, Xb, 8388608 / 4);
    transpose_cvt<<<dim3(3072 / 32, 1024 / 32), 256, 0, stream>>>(W_qkv, Wqt, 1024, 3072);
    transpose_cvt<<<dim3(1024 / 32, 1024 / 32), 256, 0, stream>>>(W_proj, Wpt, 1024, 1024);
    mask_flags<<<512, 256, 0, stream>>>(attn_mask, flags);
    pad_flags<<<1, 128, 0, stream>>>(padding, flags + 512);

    gemm_bf16<<<dim3(3072 / 128, 8192 / 128), 256, 0, stream>>>(
        Xb, Wqt, 0, q_ws, k_ws, v_ws, nullptr, nullptr);

    flash_attn<<<dim3(16, 64), 256, 0, stream>>>(
        q_ws, k_ws, v_ws, flags, flags + 512, padding, attn_mask, xbuf);

    gemm_bf16<<<dim3(1024 / 128, 8192 / 128), 256, 0, stream>>>(
        xbuf, Wpt, 1, nullptr, nullptr, nullptr, out, b_proj);
}